// Round 1
// baseline (606.854 us; speedup 1.0000x reference)
//
#include <hip/hip_runtime.h>
#include <cstdint>

#define THREADS 256
static constexpr int BS   = 4096;
static constexpr int C    = 16384;
static constexpr int D    = 128;
static constexpr int HALF = 2048;   // rows 0..2047 pair with rows 2048..4095
static constexpr int NPOS = 4;
static constexpr int NNEG = 20;
static constexpr int NSEL = 24;
static constexpr int QPT  = 16;     // int4 quads per thread (16*4 = 64 cols)

// ---- JAX threefry2x32 (20 rounds), key = PRNGKey(42) = [0, 42] ----
__device__ __forceinline__ void tf2x32(uint32_t x0, uint32_t x1,
                                       uint32_t& o0, uint32_t& o1) {
  constexpr uint32_t ks0 = 0u, ks1 = 42u;
  constexpr uint32_t ks2 = 0x1BD11BDAu ^ ks0 ^ ks1;
  x0 += ks0; x1 += ks1;
#define TFR(r) { x0 += x1; x1 = (x1 << (r)) | (x1 >> (32 - (r))); x1 ^= x0; }
  TFR(13) TFR(15) TFR(26) TFR(6)
  x0 += ks1; x1 += ks2 + 1u;
  TFR(17) TFR(29) TFR(16) TFR(24)
  x0 += ks2; x1 += ks0 + 2u;
  TFR(13) TFR(15) TFR(26) TFR(6)
  x0 += ks0; x1 += ks1 + 3u;
  TFR(17) TFR(29) TFR(16) TFR(24)
  x0 += ks1; x1 += ks2 + 4u;
  TFR(13) TFR(15) TFR(26) TFR(6)
  x0 += ks2; x1 += ks0 + 5u;
#undef TFR
  o0 = x0; o1 = x1;
}

// composite key: (bits23+1) << 14 | (16383-col). Larger = better;
// equal bits -> smaller col wins (matches jax.lax.top_k tie-break).
// 0 is the "no candidate" sentinel (real comps are >= 1<<14).
__device__ __forceinline__ uint64_t mkcomp(uint32_t bits, int c) {
  return (((uint64_t)(bits >> 9) + 1ull) << 14) | (uint64_t)(16383 - c);
}

__device__ __forceinline__ void ins3(uint64_t v, uint64_t& a, uint64_t& b, uint64_t& c) {
  if (v > c) {
    if (v > a)      { c = b; b = a; a = v; }
    else if (v > b) { c = b; b = v; }
    else            { c = v; }
  }
}

// Iterative argmax selection of NNEG negatives for one row.
// t0..t2: this thread's cached top-3 comps. sel[0..3] already holds the
// positives (sorted); sel[4..23] is filled here.
__device__ void select_negs(uint64_t t0, uint64_t t1, uint64_t t2,
                            int* sel, int rbase, int hi,
                            uint64_t* best, uint64_t* winner_s) {
  const int tid = threadIdx.x;
  best[tid] = (t0 << 8) | (uint64_t)tid;   // pack owner tid in low 8 bits
  __syncthreads();
  for (int it = 0; it < NNEG; ++it) {
    if (tid < 64) {
      uint64_t m = best[tid];
      uint64_t x = best[tid + 64];  if (x > m) m = x;
      x = best[tid + 128];          if (x > m) m = x;
      x = best[tid + 192];          if (x > m) m = x;
#pragma unroll
      for (int o = 32; o; o >>= 1) {
        uint64_t y = (uint64_t)__shfl_xor((unsigned long long)m, o, 64);
        if (y > m) m = y;
      }
      if (tid == 0) *winner_s = m;
    }
    __syncthreads();
    const uint64_t w = *winner_s;
    const int wtid = (int)(w & 0xFFull);
    const int wcol = 16383 - (int)((w >> 8) & 0x3FFFull);
    if (tid == 0) sel[NPOS + it] = wcol;
    if (tid == wtid) {
      t0 = t1; t1 = t2; t2 = 0;
      if (t0 == 0) {
        // rare: cached top-3 exhausted -> rebuild from scratch, excluding
        // positives (sel[0..3]), previously picked negs, and current wcol.
        for (int j = 0; j < QPT; ++j) {
#pragma unroll
          for (int i = 0; i < 4; ++i) {
            const int c = ((j * THREADS + tid) << 2) + i;
            bool skip = (c == wcol);
            for (int k = 0; k < NPOS + it; ++k) skip = skip || (sel[k] == c);
            if (!skip) {
              uint32_t o0, o1;
              tf2x32((uint32_t)(rbase + c), (uint32_t)(rbase + c) + 0x2000000u, o0, o1);
              ins3(mkcomp(hi ? o1 : o0, c), t0, t1, t2);
            }
          }
        }
      }
      best[tid] = (t0 << 8) | (uint64_t)tid;
    }
    __syncthreads();
  }
}

// sim + BCE for one row given its 24 selected columns; writes mean-BCE to ws[row].
__device__ void row_phase3(const float* __restrict__ feat, const float* __restrict__ proto,
                           const int* sel, int row, float* __restrict__ out_ws,
                           float* ff, float* normf_s, float* bces) {
  const int tid = threadIdx.x;
  __syncthreads();                       // protect ff/bces reuse across calls
  if (tid < D) ff[tid] = feat[(size_t)row * D + tid];
  __syncthreads();
  if (tid < 64) {
    float a = ff[tid], b = ff[tid + 64];
    float s = a * a + b * b;
#pragma unroll
    for (int o = 32; o; o >>= 1) s += __shfl_xor(s, o, 64);
    if (tid == 0) *normf_s = s;
  }
  __syncthreads();
  const int g = tid >> 3, k = tid & 7;   // 24 groups x 8 lanes (g<24 active)
  if (g < NSEL) {
    const int c = sel[g];
    const float4* pc = reinterpret_cast<const float4*>(proto + (size_t)c * D);
    float fp = 0.f, pp = 0.f;
#pragma unroll
    for (int qq = 0; qq < 4; ++qq) {
      const float4 pv = pc[k * 4 + qq];
      const int d0 = k * 16 + qq * 4;
      fp += ff[d0] * pv.x + ff[d0 + 1] * pv.y + ff[d0 + 2] * pv.z + ff[d0 + 3] * pv.w;
      pp += pv.x * pv.x + pv.y * pv.y + pv.z * pv.z + pv.w * pv.w;
    }
    fp += __shfl_xor(fp, 1, 64); pp += __shfl_xor(pp, 1, 64);
    fp += __shfl_xor(fp, 2, 64); pp += __shfl_xor(pp, 2, 64);
    fp += __shfl_xor(fp, 4, 64); pp += __shfl_xor(pp, 4, 64);
    if (k == 0) {
      const float x = (*normf_s) * pp;
      float rn = rsqrtf(x);
      rn = rn * (1.5f - 0.5f * x * rn * rn);   // 1 NR step for accuracy
      const float l = fp * rn * 10.0f;          // /TEMP, TEMP=0.1
      const float tgt = (g < NPOS) ? 0.25f : 0.0f;
      bces[g] = fmaxf(l, 0.f) - l * tgt + log1pf(expf(-fabsf(l)));
    }
  }
  __syncthreads();
  if (tid == 0) {
    float s = 0.f;
#pragma unroll
    for (int i = 0; i < NSEL; ++i) s += bces[i];
    out_ws[row] = s * (1.0f / NSEL);
  }
}

__global__ __launch_bounds__(THREADS) void supcon_main(
    const float* __restrict__ feat, const float* __restrict__ proto,
    const int* __restrict__ lab, float* __restrict__ row_ws) {
  __shared__ uint64_t best[THREADS];
  __shared__ uint64_t winner_s;
  __shared__ int selL[NSEL], selH[NSEL];
  __shared__ int posCnt[2];
  __shared__ int posBuf[2][8];
  __shared__ float ff[D];
  __shared__ float normf_s;
  __shared__ float bces[NSEL];

  const int tid = threadIdx.x;
  const int r = blockIdx.x;          // low row; pairs with r+HALF
  const int rbase = r * C;           // < 2^25, also the threefry x0 base

  if (tid == 0) { posCnt[0] = 0; posCnt[1] = 0; }
  __syncthreads();

  uint64_t L0 = 0, L1 = 0, L2 = 0, H0 = 0, H1 = 0, H2 = 0;
  const int4* labL4 = reinterpret_cast<const int4*>(lab + (size_t)rbase);
  const int4* labH4 = reinterpret_cast<const int4*>(lab + (size_t)rbase + (size_t)HALF * C);

  for (int j = 0; j < QPT; ++j) {
    const int q = j * THREADS + tid;
    const int4 lL = labL4[q];
    const int4 lH = labH4[q];
    const int c0 = q << 2;
    uint32_t o0, o1;
#define DOCOL(i, LX, HX) {                                                   \
    const int c = c0 + (i);                                                  \
    tf2x32((uint32_t)(rbase + c), (uint32_t)(rbase + c) + 0x2000000u, o0, o1); \
    if (LX) { int s = atomicAdd(&posCnt[0], 1); if (s < 8) posBuf[0][s] = c; } \
    else ins3(mkcomp(o0, c), L0, L1, L2);                                    \
    if (HX) { int s = atomicAdd(&posCnt[1], 1); if (s < 8) posBuf[1][s] = c; } \
    else ins3(mkcomp(o1, c), H0, H1, H2); }
    DOCOL(0, lL.x, lH.x)
    DOCOL(1, lL.y, lH.y)
    DOCOL(2, lL.z, lH.z)
    DOCOL(3, lL.w, lH.w)
#undef DOCOL
  }
  __syncthreads();
  if (tid < 2) {       // sort the 4 positive cols (deterministic slot order)
    int a = posBuf[tid][0], b = posBuf[tid][1], c2 = posBuf[tid][2], d = posBuf[tid][3];
#define CSW(x, y) if (x > y) { int t_ = x; x = y; y = t_; }
    CSW(a, b) CSW(c2, d) CSW(a, c2) CSW(b, d) CSW(b, c2)
#undef CSW
    int* s = tid ? selH : selL;
    s[0] = a; s[1] = b; s[2] = c2; s[3] = d;
  }
  // (visibility of selL/selH guaranteed by the barrier inside select_negs)
  select_negs(L0, L1, L2, selL, rbase, 0, best, &winner_s);
  select_negs(H0, H1, H2, selH, rbase, 1, best, &winner_s);

  row_phase3(feat, proto, selL, r,        row_ws, ff, &normf_s, bces);
  row_phase3(feat, proto, selH, r + HALF, row_ws, ff, &normf_s, bces);
}

__global__ __launch_bounds__(THREADS) void supcon_reduce(
    const float* __restrict__ ws, float* __restrict__ out) {
  __shared__ float red[THREADS];
  const int tid = threadIdx.x;
  float s = 0.f;
#pragma unroll
  for (int j = 0; j < BS / THREADS; ++j) s += ws[j * THREADS + tid];
  red[tid] = s;
  __syncthreads();
  for (int o = THREADS / 2; o > 0; o >>= 1) {
    if (tid < o) red[tid] += red[tid + o];
    __syncthreads();
  }
  if (tid == 0) out[0] = red[0] * (1.0f / BS);
}

extern "C" void kernel_launch(void* const* d_in, const int* in_sizes, int n_in,
                              void* d_out, int out_size, void* d_ws, size_t ws_size,
                              hipStream_t stream) {
  (void)in_sizes; (void)n_in; (void)out_size; (void)ws_size;
  const float* feat  = (const float*)d_in[0];
  const float* proto = (const float*)d_in[1];
  const int*   lab   = (const int*)d_in[2];
  float* out = (float*)d_out;
  float* ws  = (float*)d_ws;   // 4096 per-row mean-BCE values

  supcon_main<<<dim3(HALF), dim3(THREADS), 0, stream>>>(feat, proto, lab, ws);
  supcon_reduce<<<dim3(1), dim3(THREADS), 0, stream>>>(ws, out);
}